// Round 8
// baseline (101.029 us; speedup 1.0000x reference)
//
#include <hip/hip_runtime.h>
#include <hip/hip_bf16.h>

typedef short bf16x8 __attribute__((ext_vector_type(8)));
typedef float f32x4  __attribute__((ext_vector_type(4)));

#define KSZ   7
#define KK    49
#define GCH   16
#define CIN   256
#define MID   64
#define NGRP  16
#define WID   56
#define HWSZ  3136
#define NB    4
#define NPIX  (NB * HWSZ)
#define EPSV  1e-5f

// ws layout (floats):
// [0..63] sum | [64..127] sumsq | [128..191] a | [192..255] c
// [256 .. 256+16384)   w1T  [CIN][MID]   (transposed w1)
// [16640 ...]          t    [MID][NPIX]  (plane-major)
#define WS_W1T 256
#define WS_T   (256 + CIN * MID)

__global__ __launch_bounds__(256) void k0_transpose(const float* __restrict__ w1,
                                                    float* __restrict__ ws) {
    const int i = blockIdx.x * 256 + threadIdx.x;   // 16384 = CIN*MID
    const int c = i >> 6;
    const int o = i & 63;
    ws[WS_W1T + i] = w1[o * CIN + c];               // w1T[c][o] = w1[o][c]
}

__global__ __launch_bounds__(256) void k1_conv1(const float* __restrict__ x,
                                                const float* __restrict__ b1,
                                                float* __restrict__ ws) {
    const int tid = threadIdx.x;
    const int pix = blockIdx.x * 256 + tid;         // 49 blocks * 256
    const int ob  = blockIdx.y * 4;                 // 16 chunks of 4
    const int b   = pix / HWSZ;
    const int hw  = pix - b * HWSZ;

    float acc[4];
#pragma unroll
    for (int i = 0; i < 4; ++i) acc[i] = b1[ob + i];

    const float* xp = x + (size_t)b * CIN * HWSZ + hw;
    const float* wT = ws + WS_W1T + ob;
#pragma unroll 16
    for (int c = 0; c < CIN; ++c) {
        const float4 wv = *(const float4*)(wT + c * MID);   // uniform s_load_dwordx4
        const float  xv = xp[(size_t)c * HWSZ];
        acc[0] = fmaf(wv.x, xv, acc[0]);
        acc[1] = fmaf(wv.y, xv, acc[1]);
        acc[2] = fmaf(wv.z, xv, acc[2]);
        acc[3] = fmaf(wv.w, xv, acc[3]);
    }

    float* tp = ws + WS_T + (size_t)ob * NPIX + pix;
#pragma unroll
    for (int i = 0; i < 4; ++i) tp[(size_t)i * NPIX] = acc[i];

    __shared__ float bs[4];
    __shared__ float bq[4];
    if (tid < 4) { bs[tid] = 0.f; bq[tid] = 0.f; }
    __syncthreads();
#pragma unroll
    for (int i = 0; i < 4; ++i) {
        float s = acc[i];
        float qq = acc[i] * acc[i];
#pragma unroll
        for (int m = 1; m < 64; m <<= 1) {
            s  += __shfl_xor(s, m, 64);
            qq += __shfl_xor(qq, m, 64);
        }
        if ((tid & 63) == 0) { atomicAdd(&bs[i], s); atomicAdd(&bq[i], qq); }
    }
    __syncthreads();
    if (tid < 4) {
        atomicAdd(&ws[ob + tid],      bs[tid]);
        atomicAdd(&ws[64 + ob + tid], bq[tid]);
    }
}

__global__ void k2_stats(float* __restrict__ ws,
                         const float* __restrict__ gamma,
                         const float* __restrict__ beta) {
    const int o = threadIdx.x;  // 64
    const float n   = (float)NPIX;
    const float mu  = ws[o] / n;
    const float var = ws[64 + o] / n - mu * mu;
    const float a   = gamma[o] * rsqrtf(var + EPSV);
    ws[128 + o] = a;
    ws[192 + o] = beta[o] - mu * a;
}

// Block = 128 px x 4 slots (512 thr, 8 waves), grid (98,16).
// Phase A = MFMA: D[64 taps][128 px] = W2g[64x64(bf16)] * T[64x128(bf16)].
// tlb/wb padded to 72 shorts/row (144 B) -> conflict-free b128 fragment reads.
__global__ __launch_bounds__(512) void k3_fused(const float* __restrict__ x,
                                                const float* __restrict__ w2,
                                                const float* __restrict__ b2,
                                                const float* __restrict__ ws,
                                                float* __restrict__ out) {
    __shared__ unsigned short tlb[128][72];   // T bf16: [px][k]   18432 B
    __shared__ unsigned short wb[64][72];     // W2 bf16: [tap][k]  9216 B
    __shared__ float swgt[128][52];           // D fp32: [px][tap] 26624 B
    const int tid  = threadIdx.x;
    const int p    = tid & 127;               // local pixel
    const int q    = tid >> 7;                // slot 0..3
    const int lane = tid & 63;
    const int wave = tid >> 6;                // 0..7
    const int g    = blockIdx.y;
    const int pix  = blockIdx.x * 128 + p;

    // ---- stage T: BN+ReLU -> bf16, thread covers k = q*16 .. q*16+15 of px p
    {
        const float* tcol = ws + WS_T + blockIdx.x * 128 + p;
        bf16x8 v0, v1;
#pragma unroll
        for (int i = 0; i < 16; ++i) {
            const int o = q * 16 + i;
            float v = tcol[(size_t)o * NPIX];                 // coalesced
            v = fmaxf(0.f, fmaf(ws[128 + o], v, ws[192 + o]));
            __hip_bfloat16 hb = __float2bfloat16(v);
            const short s = *reinterpret_cast<short*>(&hb);
            if (i < 8) v0[i & 7] = s; else v1[i & 7] = s;
        }
        *(bf16x8*)&tlb[p][q * 16]     = v0;
        *(bf16x8*)&tlb[p][q * 16 + 8] = v1;
    }

    // ---- stage W2 (bf16), rows 49..63 zeroed
    for (int e = tid; e < 64 * 64; e += 512) {
        const int row = e >> 6;
        const int k   = e & 63;
        const float v = (row < KK) ? w2[((size_t)g * KK + row) * MID + k] : 0.f;
        __hip_bfloat16 hb = __float2bfloat16(v);
        wb[row][k] = *reinterpret_cast<unsigned short*>(&hb);
    }
    __syncthreads();

    // ---- MFMA: wave handles m = wave>>1, n-tiles (wave&1)*4 .. +4
    {
        const int m  = wave >> 1;
        const int n0 = (wave & 1) * 4;
        const int r  = lane & 15;
        const int hi = lane >> 4;
        f32x4 acc[4] = {{0,0,0,0},{0,0,0,0},{0,0,0,0},{0,0,0,0}};
#pragma unroll
        for (int ks = 0; ks < 2; ++ks) {
            const bf16x8 af = *(const bf16x8*)&wb[m * 16 + r][ks * 32 + hi * 8];
#pragma unroll
            for (int ni = 0; ni < 4; ++ni) {
                const bf16x8 bfv = *(const bf16x8*)&tlb[(n0 + ni) * 16 + r][ks * 32 + hi * 8];
                acc[ni] = __builtin_amdgcn_mfma_f32_16x16x32_bf16(af, bfv, acc[ni], 0, 0, 0);
            }
        }
        // D: col(px-within-tile)=lane&15, row(tap-within-tile)=(lane>>4)*4+j
#pragma unroll
        for (int ni = 0; ni < 4; ++ni) {
            const int px = (n0 + ni) * 16 + r;
#pragma unroll
            for (int j = 0; j < 4; ++j) {
                const int tap = m * 16 + hi * 4 + j;
                if (tap < KK) swgt[px][tap] = acc[ni][j];
            }
        }
    }
    __syncthreads();

    // ---- Phase B: involution, slot q applies 49 taps to channels q*4..q*4+3
    const int b  = pix / HWSZ;
    const int hw = pix - b * HWSZ;
    const int h  = hw / WID;
    const int w  = hw - h * WID;
    const float* xq   = x + ((size_t)b * CIN + g * GCH + q * 4) * HWSZ;
    const float* bias = b2 + g * KK;                 // uniform -> s_load

    float a0 = 0.f, a1 = 0.f, a2 = 0.f, a3 = 0.f;
    bool colok[7];
#pragma unroll
    for (int j = 0; j < 7; ++j) colok[j] = (unsigned)(w + j - 3) < 56u;

#pragma unroll
    for (int r7 = 0; r7 < 7; ++r7) {
        const bool rowok = (unsigned)(h + r7 - 3) < 56u;
        const int  roff  = hw + (r7 - 3) * WID - 3;  // unclamped
#pragma unroll
        for (int j = 0; j < 7; ++j) {
            const int   t   = r7 * 7 + j;
            const float wgv = swgt[p][t] + bias[t];
            const float wm  = (rowok && colok[j]) ? wgv : 0.f;
            int idx = roff + j;
            idx = idx < 0 ? 0 : idx;
            idx = idx > (HWSZ - 1) ? (HWSZ - 1) : idx;   // in-buffer for masked taps
            a0 = fmaf(wm, xq[idx],            a0);
            a1 = fmaf(wm, xq[idx + HWSZ],     a1);
            a2 = fmaf(wm, xq[idx + 2 * HWSZ], a2);
            a3 = fmaf(wm, xq[idx + 3 * HWSZ], a3);
        }
    }

    float* ob = out + ((size_t)b * CIN + g * GCH + q * 4) * HWSZ + hw;
    ob[0]        = a0;
    ob[HWSZ]     = a1;
    ob[2 * HWSZ] = a2;
    ob[3 * HWSZ] = a3;
}

extern "C" void kernel_launch(void* const* d_in, const int* in_sizes, int n_in,
                              void* d_out, int out_size, void* d_ws, size_t ws_size,
                              hipStream_t stream) {
    const float* x     = (const float*)d_in[0];
    const float* w1    = (const float*)d_in[1];
    const float* b1    = (const float*)d_in[2];
    const float* gamma = (const float*)d_in[3];
    const float* beta  = (const float*)d_in[4];
    const float* w2    = (const float*)d_in[5];
    const float* b2    = (const float*)d_in[6];
    float* out = (float*)d_out;
    float* ws  = (float*)d_ws;

    hipMemsetAsync(ws, 0, 128 * sizeof(float), stream);

    k0_transpose<<<dim3(64), 256, 0, stream>>>(w1, ws);
    k1_conv1<<<dim3(49, 16), 256, 0, stream>>>(x, b1, ws);
    k2_stats<<<1, 64, 0, stream>>>(ws, gamma, beta);
    k3_fused<<<dim3(98, 16), 512, 0, stream>>>(x, w2, b2, ws, out);
}